// Round 16
// baseline (162.322 us; speedup 1.0000x reference)
//
#include <hip/hip_runtime.h>
#include <hip/hip_bf16.h>

#define NH 16
#define HD 64
#define T_SEQ 2048
#define DM 1024

typedef __attribute__((ext_vector_type(8))) short short8;
typedef __attribute__((ext_vector_type(4))) short sh4;
typedef __attribute__((ext_vector_type(4))) float f32x4;
typedef __attribute__((ext_vector_type(16))) float f32x16;
typedef unsigned short ushort;

static __device__ __forceinline__ ushort f2bf(float f) {
    union { float f; unsigned int u; } c; c.f = f;
    unsigned int r = (c.u + 0x7fffu + ((c.u >> 16) & 1u)) >> 16;
    return (ushort)r;
}

// async global->LDS, 16B per lane (wave-uniform LDS base; HW writes lane i at base+i*16)
static __device__ __forceinline__ void gload16(const ushort* g, ushort* l) {
    __builtin_amdgcn_global_load_lds(
        (const __attribute__((address_space(1))) void*)(const void*)g,
        (__attribute__((address_space(3))) void*)(void*)l, 16, 0, 0);
}

// ---------------- prep: X f32->bf16 (blocks 0..4095) + W_qkv transpose (blocks 4096+) ----
__global__ __launch_bounds__(256) void prep(const float* __restrict__ X,
                                            ushort* __restrict__ Xb,
                                            const float* __restrict__ W,
                                            ushort* __restrict__ Wt) {
    __shared__ float Ts[64][65];
    const int tid = threadIdx.x;
    if (blockIdx.x < 4096) {
        int i = blockIdx.x * 256 + tid;
        const float* s = X + (size_t)i * 8;
        float4 a = *(const float4*)(s);
        float4 b = *(const float4*)(s + 4);
        short8 o;
        o[0] = f2bf(a.x); o[1] = f2bf(a.y); o[2] = f2bf(a.z); o[3] = f2bf(a.w);
        o[4] = f2bf(b.x); o[5] = f2bf(b.y); o[6] = f2bf(b.z); o[7] = f2bf(b.w);
        *(short8*)(Xb + (size_t)i * 8) = o;
    } else {
        const int bid = blockIdx.x - 4096;
        const int N = 3 * DM;
        const int n0 = (bid % 48) * 64, k0 = (bid / 48) * 64;
        const int cg = tid & 15, r4 = tid >> 4;
        #pragma unroll
        for (int i = 0; i < 4; ++i) {
            int r = r4 + i * 16;
            float4 v = *(const float4*)(W + (size_t)(k0 + r) * N + n0 + cg * 4);
            Ts[r][cg * 4 + 0] = v.x; Ts[r][cg * 4 + 1] = v.y;
            Ts[r][cg * 4 + 2] = v.z; Ts[r][cg * 4 + 3] = v.w;
        }
        __syncthreads();
        #pragma unroll
        for (int i = 0; i < 4; ++i) {
            int r = r4 + i * 16;
            sh4 o;
            o[0] = (short)f2bf(Ts[cg * 4 + 0][r]);
            o[1] = (short)f2bf(Ts[cg * 4 + 1][r]);
            o[2] = (short)f2bf(Ts[cg * 4 + 2][r]);
            o[3] = (short)f2bf(Ts[cg * 4 + 3][r]);
            *(sh4*)(Wt + (size_t)(n0 + r) * DM + k0 + cg * 4) = o;
        }
    }
}

// ---------------- transpose + convert: W[1024][N] f32 -> Wt[N][1024] bf16 ----------------
__global__ __launch_bounds__(256) void transpose_w(const float* __restrict__ W,
                                                   ushort* __restrict__ Wt, int N) {
    __shared__ float Ts[64][65];
    const int n0 = blockIdx.x * 64, k0 = blockIdx.y * 64;
    const int tid = threadIdx.x;
    const int cg = tid & 15, r4 = tid >> 4;
    #pragma unroll
    for (int i = 0; i < 4; ++i) {
        int r = r4 + i * 16;
        float4 v = *(const float4*)(W + (size_t)(k0 + r) * N + n0 + cg * 4);
        Ts[r][cg * 4 + 0] = v.x; Ts[r][cg * 4 + 1] = v.y;
        Ts[r][cg * 4 + 2] = v.z; Ts[r][cg * 4 + 3] = v.w;
    }
    __syncthreads();
    #pragma unroll
    for (int i = 0; i < 4; ++i) {
        int r = r4 + i * 16;
        sh4 o;
        o[0] = (short)f2bf(Ts[cg * 4 + 0][r]);
        o[1] = (short)f2bf(Ts[cg * 4 + 1][r]);
        o[2] = (short)f2bf(Ts[cg * 4 + 2][r]);
        o[3] = (short)f2bf(Ts[cg * 4 + 3][r]);
        *(sh4*)(Wt + (size_t)(n0 + r) * DM + k0 + cg * 4) = o;
    }
}

// ---------------- R11 GEMM core: A+B dbuf gload_lds, counted vmcnt(8) ----------------
static __device__ __forceinline__ void gemm_core(
    const ushort* __restrict__ A, const ushort* __restrict__ Bt,
    ushort* __restrict__ smem, int m0, int n0, f32x4 acc[4][4])
{
    const int tid = threadIdx.x;
    const int wid = tid >> 6, lane = tid & 63;
    const int lr = lane & 15, g = lane >> 4;
    const int wm = wid >> 1, wn = wid & 1;
    const int lrow = lane >> 3, lslot = lane & 7;

    auto stage = [&](int b, int kt) {
        ushort* As = smem + b * 16384;
        ushort* Bs = As + 8192;
        #pragma unroll
        for (int i = 0; i < 4; ++i) {
            const int row = wid * 32 + i * 8 + lrow;
            const int gcol = (lslot ^ (row & 7)) * 8;
            const int ldsoff = (wid * 32 + i * 8) * 64;
            gload16(A  + (size_t)(m0 + row) * DM + kt * 64 + gcol, As + ldsoff);
            gload16(Bt + (size_t)(n0 + row) * DM + kt * 64 + gcol, Bs + ldsoff);
        }
    };

    stage(0, 0);
    #pragma unroll 1
    for (int kt = 0; kt < 16; ++kt) {
        const int cur = kt & 1;
        if (kt < 15) {
            stage(cur ^ 1, kt + 1);
            asm volatile("s_waitcnt vmcnt(8)" ::: "memory");
        } else {
            asm volatile("s_waitcnt vmcnt(0)" ::: "memory");
        }
        __builtin_amdgcn_s_barrier();
        __builtin_amdgcn_sched_barrier(0);
        const ushort* As = smem + cur * 16384;
        const ushort* Bs = As + 8192;
        #pragma unroll
        for (int ks = 0; ks < 2; ++ks) {
            short8 af[4], bfr[4];
            #pragma unroll
            for (int mi = 0; mi < 4; ++mi) {
                int row = wm * 64 + mi * 16 + lr;
                af[mi] = *(const short8*)(As + row * 64 + (((ks * 4 + g) ^ (row & 7)) * 8));
            }
            #pragma unroll
            for (int ni = 0; ni < 4; ++ni) {
                int row = wn * 64 + ni * 16 + lr;
                bfr[ni] = *(const short8*)(Bs + row * 64 + (((ks * 4 + g) ^ (row & 7)) * 8));
            }
            #pragma unroll
            for (int mi = 0; mi < 4; ++mi)
                #pragma unroll
                for (int ni = 0; ni < 4; ++ni)
                    acc[mi][ni] = __builtin_amdgcn_mfma_f32_16x16x32_bf16(af[mi], bfr[ni], acc[mi][ni], 0, 0, 0);
        }
        __builtin_amdgcn_sched_barrier(0);
        __builtin_amdgcn_s_barrier();
    }
}

// ---------------- Kernel 1: QKV GEMM ----------------
__global__ __launch_bounds__(256) void qkv_mfma(
    const ushort* __restrict__ Xb, const ushort* __restrict__ Wqt,
    const float* __restrict__ bias,
    ushort* __restrict__ Qb, ushort* __restrict__ Kb, ushort* __restrict__ Vt)
{
    __shared__ __align__(16) ushort smem[32768];
    const int m0 = blockIdx.y * 128;
    const int n0 = blockIdx.x * 128;
    f32x4 acc[4][4] = {};
    gemm_core(Xb, Wqt, smem, m0, n0, acc);

    const int tid = threadIdx.x;
    const int wid = tid >> 6, lane = tid & 63;
    const int lr = lane & 15, g = lane >> 4;
    const int wm = wid >> 1, wn = wid & 1;
    const int which = n0 >> 10;
    const int bq = m0 >> 11;

    if (which < 2) {
        ushort* dst = which ? Kb : Qb;
        const float sc = which ? 1.0f : 0.125f * 1.44269504f;   // Q: 1/sqrt(64) * log2e
        #pragma unroll
        for (int ni = 0; ni < 4; ++ni) {
            int nn = n0 + wn * 64 + ni * 16 + lr;
            const float bv = bias[nn];
            const int hh = (nn & 1023) >> 6, dd = nn & 63;
            const size_t hb = ((size_t)(bq * NH + hh)) * T_SEQ;
            #pragma unroll
            for (int mi = 0; mi < 4; ++mi)
                #pragma unroll
                for (int r = 0; r < 4; ++r) {
                    int t = (m0 + wm * 64 + mi * 16 + g * 4 + r) & 2047;
                    dst[(hb + t) * HD + dd] = f2bf((acc[mi][ni][r] + bv) * sc);
                }
        }
    } else {
        __syncthreads();
        ushort* Ct = smem;   // 32 KB
        #pragma unroll
        for (int ni = 0; ni < 4; ++ni) {
            int lcol = wn * 64 + ni * 16 + lr;
            const float bv = bias[n0 + lcol];
            #pragma unroll
            for (int mi = 0; mi < 4; ++mi)
                #pragma unroll
                for (int r = 0; r < 4; ++r)
                    Ct[(wm * 64 + mi * 16 + g * 4 + r) * 128 + lcol] = f2bf(acc[mi][ni][r] + bv);
        }
        __syncthreads();
        const int dloc = tid >> 1, th = (tid & 1) * 64;
        const int nn = (n0 & 1023) + dloc;
        ushort* dst = Vt + ((size_t)(bq * 1024 + nn)) * T_SEQ + (m0 & 2047) + th;
        #pragma unroll
        for (int e8 = 0; e8 < 8; ++e8) {
            short8 v;
            #pragma unroll
            for (int u = 0; u < 8; ++u) v[u] = (short)Ct[(th + e8 * 8 + u) * 128 + dloc];
            *(short8*)(dst + e8 * 8) = v;
        }
    }
}

// ---------------- Kernel 3: output projection ----------------
__global__ __launch_bounds__(256) void proj_mfma(
    const ushort* __restrict__ AO, const ushort* __restrict__ Wpt,
    const float* __restrict__ bias, float* __restrict__ Y)
{
    __shared__ __align__(16) ushort smem[32768];
    const int m0 = blockIdx.y * 128;
    const int n0 = blockIdx.x * 128;
    f32x4 acc[4][4] = {};
    gemm_core(AO, Wpt, smem, m0, n0, acc);

    const int tid = threadIdx.x;
    const int wid = tid >> 6, lane = tid & 63;
    const int lr = lane & 15, g = lane >> 4;
    const int wm = wid >> 1, wn = wid & 1;
    #pragma unroll
    for (int ni = 0; ni < 4; ++ni) {
        int nn = n0 + wn * 64 + ni * 16 + lr;
        const float bv = bias[nn];
        #pragma unroll
        for (int mi = 0; mi < 4; ++mi)
            #pragma unroll
            for (int r = 0; r < 4; ++r) {
                int m = m0 + wm * 64 + mi * 16 + g * 4 + r;
                Y[(size_t)m * DM + nn] = acc[mi][ni][r] + bv;
            }
    }
}

// ---------------- Kernel 2: 32x32 swapped-QK^T attention, gload_lds staging ----------
// K/V staged via global_load_lds (pre-swizzled source), dbuf, counted vmcnt(4) —
// same proven skeleton as gemm_core. Waves 0-1 stage K slots, waves 2-3 stage V slots.
__global__ __launch_bounds__(256) void attn_mfma(
    const ushort* __restrict__ Qb,   // [bh][t][64], pre-scaled by log2e/8
    const ushort* __restrict__ Kb,   // [bh][t][64]
    const ushort* __restrict__ Vt,   // [bh][d][2048]
    ushort* __restrict__ AO)         // [b*2048 + t][1024] bf16
{
    __shared__ __align__(16) ushort Ks[2][4096];
    __shared__ __align__(16) ushort Vs[2][4096];   // [d][k], swizzled

    const int bh = blockIdx.x;
    const int j = 15 - blockIdx.y;                 // heavy-first
    const int tid = threadIdx.x;
    const int wid = tid >> 6;
    const int lane = tid & 63;
    const int ql = lane & 31;                      // q column
    const int hi = lane >> 5;                      // 0/1

    const ushort* Kg = Kb + (size_t)bh * T_SEQ * HD;
    const ushort* Vg = Vt + (size_t)bh * HD * T_SEQ;

    const int b = bh >> 4, h = bh & 15;
    ushort* AOg = AO + (size_t)b * T_SEQ * DM + h * HD;

    const int q0 = j * 128;
    const int qlo = q0 + wid * 32;
    const int ntiles = 2 * j + 2;

    // staging geometry: 16 slots x (8 rows x 128B = 1KB); slot s = wid*4+i.
    // s<8 -> K rows s*8..+8 ; s>=8 -> V rows (s-8)*8..+8. lane l: row+=l>>3, 16B col (l&7)^(l>>3).
    const int lrow8 = lane >> 3;           // 0..7
    const int gsl = ((lane & 7) ^ lrow8) * 8;

    // Q B-frags: qb[ds] = Q[qlo+ql][ds*16 + hi*8 .. +8]
    short8 qb[4];
    {
        const ushort* Qg = Qb + ((size_t)bh * T_SEQ + qlo) * HD;
        #pragma unroll
        for (int ds = 0; ds < 4; ++ds)
            qb[ds] = *(const short8*)(Qg + (size_t)ql * HD + ds * 16 + hi * 8);
    }

    f32x16 po[2] = {};      // O^T accum
    float lp = 0.f;         // per-lane partial row sum (exact; static-max)

    auto stage = [&](int buf, int tts) {
        const int k0s = tts * 64;
        #pragma unroll
        for (int i = 0; i < 4; ++i) {
            const int s = wid * 4 + i;
            if (s < 8) {
                const int row = s * 8 + lrow8;
                gload16(Kg + (size_t)(k0s + row) * HD + gsl, &Ks[buf][s * 512]);
            } else {
                const int row = (s - 8) * 8 + lrow8;
                gload16(Vg + (size_t)row * T_SEQ + k0s + gsl, &Vs[buf][(s - 8) * 512]);
            }
        }
    };

    stage(0, 0);

    for (int tt = 0; tt < ntiles; ++tt) {
        const int k0 = tt * 64;
        const int cur = tt & 1;
        if (tt + 1 < ntiles) {
            stage(cur ^ 1, tt + 1);
            asm volatile("s_waitcnt vmcnt(4)" ::: "memory");   // tt's 4 landed (per-wave)
        } else {
            asm volatile("s_waitcnt vmcnt(0)" ::: "memory");
        }
        __builtin_amdgcn_s_barrier();
        __builtin_amdgcn_sched_barrier(0);

        if (k0 <= qlo + 31) {
            const ushort* ksb = Ks[cur];
            const ushort* vsb = Vs[cur];

            short8 vf[2][4];
            #pragma unroll
            for (int db = 0; db < 2; ++db)
                #pragma unroll
                for (int sl = 0; sl < 4; ++sl) {
                    int row = db * 32 + ql;
                    int slot = (sl * 2 + hi) ^ (row & 7);
                    vf[db][sl] = *(const short8*)(&vsb[row * 64 + slot * 8]);
                }

            f32x16 sp[2] = {};
            __builtin_amdgcn_s_setprio(1);
            #pragma unroll
            for (int kb = 0; kb < 2; ++kb) {
                #pragma unroll
                for (int ds = 0; ds < 4; ++ds) {
                    int row = kb * 32 + ql;
                    int slot = (ds * 2 + hi) ^ (row & 7);
                    short8 kf = *(const short8*)(&ksb[row * 64 + slot * 8]);
                    sp[kb] = __builtin_amdgcn_mfma_f32_32x32x16_bf16(kf, qb[ds], sp[kb], 0, 0, 0);
                }
            }
            __builtin_amdgcn_s_setprio(0);

            if (k0 + 63 > qlo) {
                #pragma unroll
                for (int kb = 0; kb < 2; ++kb) {
                    const int lim = qlo + ql - k0 - kb * 32 - 4 * hi;
                    #pragma unroll
                    for (int r = 0; r < 16; ++r) {
                        const int c = (r & 3) + 8 * (r >> 2);
                        sp[kb][r] = (c <= lim) ? sp[kb][r] : -INFINITY;
                    }
                }
            }

            float rs = 0.f;
            #pragma unroll
            for (int kb = 0; kb < 2; ++kb)
                #pragma unroll
                for (int r = 0; r < 16; ++r) {
                    float p;
                    asm("v_exp_f32 %0, %1" : "=v"(p) : "v"(sp[kb][r]));
                    sp[kb][r] = p;
                    rs += p;
                }
            lp += rs;

            #pragma unroll
            for (int kb = 0; kb < 2; ++kb) {
                #pragma unroll
                for (int ks16 = 0; ks16 < 2; ++ks16) {
                    unsigned int x0, x1, y0, y1;
                    const int rb0 = ks16 * 2, rb1 = ks16 * 2 + 1;
                    asm("v_cvt_pk_bf16_f32 %0, %1, %2" : "=v"(x0)
                        : "v"(sp[kb][4 * rb0 + 0]), "v"(sp[kb][4 * rb0 + 1]));
                    asm("v_cvt_pk_bf16_f32 %0, %1, %2" : "=v"(x1)
                        : "v"(sp[kb][4 * rb0 + 2]), "v"(sp[kb][4 * rb0 + 3]));
                    asm("v_cvt_pk_bf16_f32 %0, %1, %2" : "=v"(y0)
                        : "v"(sp[kb][4 * rb1 + 0]), "v"(sp[kb][4 * rb1 + 1]));
                    asm("v_cvt_pk_bf16_f32 %0, %1, %2" : "=v"(y1)
                        : "v"(sp[kb][4 * rb1 + 2]), "v"(sp[kb][4 * rb1 + 3]));
                    asm("v_permlane32_swap_b32 %0, %1" : "+v"(x0), "+v"(y0));
                    asm("v_permlane32_swap_b32 %0, %1" : "+v"(x1), "+v"(y1));
                    union { unsigned int w[4]; short8 s8; } pb;
                    pb.w[0] = x0; pb.w[1] = x1; pb.w[2] = y0; pb.w[3] = y1;
                    const int sl = kb * 2 + ks16;
                    __builtin_amdgcn_s_setprio(1);
                    po[0] = __builtin_amdgcn_mfma_f32_32x32x16_bf16(vf[0][sl], pb.s8, po[0], 0, 0, 0);
                    po[1] = __builtin_amdgcn_mfma_f32_32x32x16_bf16(vf[1][sl], pb.s8, po[1], 0, 0, 0);
                    __builtin_amdgcn_s_setprio(0);
                }
            }
        }
        __builtin_amdgcn_sched_barrier(0);
        __builtin_amdgcn_s_barrier();   // all reads done before next tile's DMA overwrites
    }

    lp += __shfl_xor(lp, 32);
    const float inv = 1.f / lp;
    const int q = qlo + ql;
    #pragma unroll
    for (int db = 0; db < 2; ++db) {
        #pragma unroll
        for (int rb = 0; rb < 4; ++rb) {
            unsigned int w0, w1;
            float f0 = po[db][4 * rb + 0] * inv, f1 = po[db][4 * rb + 1] * inv;
            float f2 = po[db][4 * rb + 2] * inv, f3 = po[db][4 * rb + 3] * inv;
            asm("v_cvt_pk_bf16_f32 %0, %1, %2" : "=v"(w0) : "v"(f0), "v"(f1));
            asm("v_cvt_pk_bf16_f32 %0, %1, %2" : "=v"(w1) : "v"(f2), "v"(f3));
            uint2 wv; wv.x = w0; wv.y = w1;
            *(uint2*)(AOg + (size_t)q * DM + db * 32 + 8 * rb + 4 * hi) = wv;
        }
    }
}

extern "C" void kernel_launch(void* const* d_in, const int* in_sizes, int n_in,
                              void* d_out, int out_size, void* d_ws, size_t ws_size,
                              hipStream_t stream) {
    const float* x      = (const float*)d_in[0];
    const float* W_qkv  = (const float*)d_in[1];
    const float* b_qkv  = (const float*)d_in[2];
    const float* W_proj = (const float*)d_in[3];
    const float* b_proj = (const float*)d_in[4];
    float* out = (float*)d_out;

    const size_t perbuf = (size_t)4 * NH * T_SEQ * HD;
    ushort* Qb  = (ushort*)d_ws;
    ushort* Kb  = Qb + perbuf;
    ushort* Vt  = Kb + perbuf;
    ushort* AO  = Vt + perbuf;
    ushort* Wqt = AO;                    // consumed by qkv_mfma before attn writes AO
    ushort* Wpt = Qb;                    // written after attn consumed Qb
    ushort* Xb  = (ushort*)d_out;        // d_out as scratch, overwritten by proj

    // prep: X->bf16 (4096 blocks) + W_qkv^T (768 blocks), one launch
    hipLaunchKernelGGL(prep, dim3(4096 + 768), dim3(256), 0, stream, x, Xb, W_qkv, Wqt);
    hipLaunchKernelGGL(qkv_mfma, dim3(24, 64), dim3(256), 0, stream,
                       Xb, Wqt, b_qkv, Qb, Kb, Vt);
    hipLaunchKernelGGL(attn_mfma, dim3(64, 16), dim3(256), 0, stream,
                       Qb, Kb, Vt, AO);
    hipLaunchKernelGGL(transpose_w, dim3(16, 16), dim3(256), 0, stream, W_proj, Wpt, DM);
    hipLaunchKernelGGL(proj_mfma, dim3(8, 64), dim3(256), 0, stream,
                       AO, Wpt, b_proj, out);
}

// Round 17
// 155.007 us; speedup vs baseline: 1.0472x; 1.0472x over previous
//
#include <hip/hip_runtime.h>
#include <hip/hip_bf16.h>

#define NH 16
#define HD 64
#define T_SEQ 2048
#define DM 1024

typedef __attribute__((ext_vector_type(8))) short short8;
typedef __attribute__((ext_vector_type(4))) short sh4;
typedef __attribute__((ext_vector_type(4))) float f32x4;
typedef __attribute__((ext_vector_type(16))) float f32x16;
typedef unsigned short ushort;

static __device__ __forceinline__ ushort f2bf(float f) {
    union { float f; unsigned int u; } c; c.f = f;
    unsigned int r = (c.u + 0x7fffu + ((c.u >> 16) & 1u)) >> 16;
    return (ushort)r;
}

// async global->LDS, 16B per lane (wave-uniform LDS base; HW writes lane i at base+i*16)
static __device__ __forceinline__ void gload16(const ushort* g, ushort* l) {
    __builtin_amdgcn_global_load_lds(
        (const __attribute__((address_space(1))) void*)(const void*)g,
        (__attribute__((address_space(3))) void*)(void*)l, 16, 0, 0);
}

// ---------------- prep: X f32->bf16 (blocks 0..4095) + W_qkv transpose (blocks 4096+) ----
__global__ __launch_bounds__(256) void prep(const float* __restrict__ X,
                                            ushort* __restrict__ Xb,
                                            const float* __restrict__ W,
                                            ushort* __restrict__ Wt) {
    __shared__ float Ts[64][65];
    const int tid = threadIdx.x;
    if (blockIdx.x < 4096) {
        int i = blockIdx.x * 256 + tid;
        const float* s = X + (size_t)i * 8;
        float4 a = *(const float4*)(s);
        float4 b = *(const float4*)(s + 4);
        short8 o;
        o[0] = f2bf(a.x); o[1] = f2bf(a.y); o[2] = f2bf(a.z); o[3] = f2bf(a.w);
        o[4] = f2bf(b.x); o[5] = f2bf(b.y); o[6] = f2bf(b.z); o[7] = f2bf(b.w);
        *(short8*)(Xb + (size_t)i * 8) = o;
    } else {
        const int bid = blockIdx.x - 4096;
        const int N = 3 * DM;
        const int n0 = (bid % 48) * 64, k0 = (bid / 48) * 64;
        const int cg = tid & 15, r4 = tid >> 4;
        #pragma unroll
        for (int i = 0; i < 4; ++i) {
            int r = r4 + i * 16;
            float4 v = *(const float4*)(W + (size_t)(k0 + r) * N + n0 + cg * 4);
            Ts[r][cg * 4 + 0] = v.x; Ts[r][cg * 4 + 1] = v.y;
            Ts[r][cg * 4 + 2] = v.z; Ts[r][cg * 4 + 3] = v.w;
        }
        __syncthreads();
        #pragma unroll
        for (int i = 0; i < 4; ++i) {
            int r = r4 + i * 16;
            sh4 o;
            o[0] = (short)f2bf(Ts[cg * 4 + 0][r]);
            o[1] = (short)f2bf(Ts[cg * 4 + 1][r]);
            o[2] = (short)f2bf(Ts[cg * 4 + 2][r]);
            o[3] = (short)f2bf(Ts[cg * 4 + 3][r]);
            *(sh4*)(Wt + (size_t)(n0 + r) * DM + k0 + cg * 4) = o;
        }
    }
}

// ---------------- transpose + convert: W[1024][N] f32 -> Wt[N][1024] bf16 ----------------
__global__ __launch_bounds__(256) void transpose_w(const float* __restrict__ W,
                                                   ushort* __restrict__ Wt, int N) {
    __shared__ float Ts[64][65];
    const int n0 = blockIdx.x * 64, k0 = blockIdx.y * 64;
    const int tid = threadIdx.x;
    const int cg = tid & 15, r4 = tid >> 4;
    #pragma unroll
    for (int i = 0; i < 4; ++i) {
        int r = r4 + i * 16;
        float4 v = *(const float4*)(W + (size_t)(k0 + r) * N + n0 + cg * 4);
        Ts[r][cg * 4 + 0] = v.x; Ts[r][cg * 4 + 1] = v.y;
        Ts[r][cg * 4 + 2] = v.z; Ts[r][cg * 4 + 3] = v.w;
    }
    __syncthreads();
    #pragma unroll
    for (int i = 0; i < 4; ++i) {
        int r = r4 + i * 16;
        sh4 o;
        o[0] = (short)f2bf(Ts[cg * 4 + 0][r]);
        o[1] = (short)f2bf(Ts[cg * 4 + 1][r]);
        o[2] = (short)f2bf(Ts[cg * 4 + 2][r]);
        o[3] = (short)f2bf(Ts[cg * 4 + 3][r]);
        *(sh4*)(Wt + (size_t)(n0 + r) * DM + k0 + cg * 4) = o;
    }
}

// ---------------- R11 GEMM core: A+B dbuf gload_lds, counted vmcnt(8) ----------------
static __device__ __forceinline__ void gemm_core(
    const ushort* __restrict__ A, const ushort* __restrict__ Bt,
    ushort* __restrict__ smem, int m0, int n0, f32x4 acc[4][4])
{
    const int tid = threadIdx.x;
    const int wid = tid >> 6, lane = tid & 63;
    const int lr = lane & 15, g = lane >> 4;
    const int wm = wid >> 1, wn = wid & 1;
    const int lrow = lane >> 3, lslot = lane & 7;

    auto stage = [&](int b, int kt) {
        ushort* As = smem + b * 16384;
        ushort* Bs = As + 8192;
        #pragma unroll
        for (int i = 0; i < 4; ++i) {
            const int row = wid * 32 + i * 8 + lrow;
            const int gcol = (lslot ^ (row & 7)) * 8;
            const int ldsoff = (wid * 32 + i * 8) * 64;
            gload16(A  + (size_t)(m0 + row) * DM + kt * 64 + gcol, As + ldsoff);
            gload16(Bt + (size_t)(n0 + row) * DM + kt * 64 + gcol, Bs + ldsoff);
        }
    };

    stage(0, 0);
    #pragma unroll 1
    for (int kt = 0; kt < 16; ++kt) {
        const int cur = kt & 1;
        if (kt < 15) {
            stage(cur ^ 1, kt + 1);
            asm volatile("s_waitcnt vmcnt(8)" ::: "memory");
        } else {
            asm volatile("s_waitcnt vmcnt(0)" ::: "memory");
        }
        __builtin_amdgcn_s_barrier();
        __builtin_amdgcn_sched_barrier(0);
        const ushort* As = smem + cur * 16384;
        const ushort* Bs = As + 8192;
        #pragma unroll
        for (int ks = 0; ks < 2; ++ks) {
            short8 af[4], bfr[4];
            #pragma unroll
            for (int mi = 0; mi < 4; ++mi) {
                int row = wm * 64 + mi * 16 + lr;
                af[mi] = *(const short8*)(As + row * 64 + (((ks * 4 + g) ^ (row & 7)) * 8));
            }
            #pragma unroll
            for (int ni = 0; ni < 4; ++ni) {
                int row = wn * 64 + ni * 16 + lr;
                bfr[ni] = *(const short8*)(Bs + row * 64 + (((ks * 4 + g) ^ (row & 7)) * 8));
            }
            #pragma unroll
            for (int mi = 0; mi < 4; ++mi)
                #pragma unroll
                for (int ni = 0; ni < 4; ++ni)
                    acc[mi][ni] = __builtin_amdgcn_mfma_f32_16x16x32_bf16(af[mi], bfr[ni], acc[mi][ni], 0, 0, 0);
        }
        __builtin_amdgcn_sched_barrier(0);
        __builtin_amdgcn_s_barrier();
    }
}

// ---------------- Kernel 1: QKV GEMM (XCD-swizzled grid) ----------------
__global__ __launch_bounds__(256) void qkv_mfma(
    const ushort* __restrict__ Xb, const ushort* __restrict__ Wqt,
    const float* __restrict__ bias,
    ushort* __restrict__ Qb, ushort* __restrict__ Kb, ushort* __restrict__ Vt)
{
    __shared__ __align__(16) ushort smem[32768];
    // T1: nwg=1536 (divisible by 8 XCDs); each XCD gets a contiguous chunk of 192
    // tiles = 8 consecutive M-rows -> per-XCD A working set 2MB (L2-resident).
    const int lin = blockIdx.x + 24 * blockIdx.y;
    const int swz = (lin & 7) * 192 + (lin >> 3);
    const int m0 = (swz / 24) * 128;
    const int n0 = (swz % 24) * 128;
    f32x4 acc[4][4] = {};
    gemm_core(Xb, Wqt, smem, m0, n0, acc);

    const int tid = threadIdx.x;
    const int wid = tid >> 6, lane = tid & 63;
    const int lr = lane & 15, g = lane >> 4;
    const int wm = wid >> 1, wn = wid & 1;
    const int which = n0 >> 10;
    const int bq = m0 >> 11;

    if (which < 2) {
        ushort* dst = which ? Kb : Qb;
        const float sc = which ? 1.0f : 0.125f * 1.44269504f;   // Q: 1/sqrt(64) * log2e
        #pragma unroll
        for (int ni = 0; ni < 4; ++ni) {
            int nn = n0 + wn * 64 + ni * 16 + lr;
            const float bv = bias[nn];
            const int hh = (nn & 1023) >> 6, dd = nn & 63;
            const size_t hb = ((size_t)(bq * NH + hh)) * T_SEQ;
            #pragma unroll
            for (int mi = 0; mi < 4; ++mi)
                #pragma unroll
                for (int r = 0; r < 4; ++r) {
                    int t = (m0 + wm * 64 + mi * 16 + g * 4 + r) & 2047;
                    dst[(hb + t) * HD + dd] = f2bf((acc[mi][ni][r] + bv) * sc);
                }
        }
    } else {
        __syncthreads();
        ushort* Ct = smem;   // 32 KB
        #pragma unroll
        for (int ni = 0; ni < 4; ++ni) {
            int lcol = wn * 64 + ni * 16 + lr;
            const float bv = bias[n0 + lcol];
            #pragma unroll
            for (int mi = 0; mi < 4; ++mi)
                #pragma unroll
                for (int r = 0; r < 4; ++r)
                    Ct[(wm * 64 + mi * 16 + g * 4 + r) * 128 + lcol] = f2bf(acc[mi][ni][r] + bv);
        }
        __syncthreads();
        const int dloc = tid >> 1, th = (tid & 1) * 64;
        const int nn = (n0 & 1023) + dloc;
        ushort* dst = Vt + ((size_t)(bq * 1024 + nn)) * T_SEQ + (m0 & 2047) + th;
        #pragma unroll
        for (int e8 = 0; e8 < 8; ++e8) {
            short8 v;
            #pragma unroll
            for (int u = 0; u < 8; ++u) v[u] = (short)Ct[(th + e8 * 8 + u) * 128 + dloc];
            *(short8*)(dst + e8 * 8) = v;
        }
    }
}

// ---------------- Kernel 3: output projection (XCD-swizzled grid) ----------------
__global__ __launch_bounds__(256) void proj_mfma(
    const ushort* __restrict__ AO, const ushort* __restrict__ Wpt,
    const float* __restrict__ bias, float* __restrict__ Y)
{
    __shared__ __align__(16) ushort smem[32768];
    const int lin = blockIdx.x + 8 * blockIdx.y;       // nwg=512, cpx=64
    const int swz = (lin & 7) * 64 + (lin >> 3);
    const int m0 = (swz >> 3) * 128;
    const int n0 = (swz & 7) * 128;
    f32x4 acc[4][4] = {};
    gemm_core(AO, Wpt, smem, m0, n0, acc);

    const int tid = threadIdx.x;
    const int wid = tid >> 6, lane = tid & 63;
    const int lr = lane & 15, g = lane >> 4;
    const int wm = wid >> 1, wn = wid & 1;
    #pragma unroll
    for (int ni = 0; ni < 4; ++ni) {
        int nn = n0 + wn * 64 + ni * 16 + lr;
        const float bv = bias[nn];
        #pragma unroll
        for (int mi = 0; mi < 4; ++mi)
            #pragma unroll
            for (int r = 0; r < 4; ++r) {
                int m = m0 + wm * 64 + mi * 16 + g * 4 + r;
                Y[(size_t)m * DM + nn] = acc[mi][ni][r] + bv;
            }
    }
}

// ---------------- Kernel 2: 32x32 swapped-QK^T attention, reg-staged dbuf (R15) ----------
__global__ __launch_bounds__(256) void attn_mfma(
    const ushort* __restrict__ Qb,   // [bh][t][64], pre-scaled by log2e/8
    const ushort* __restrict__ Kb,   // [bh][t][64]
    const ushort* __restrict__ Vt,   // [bh][d][2048]
    ushort* __restrict__ AO)         // [b*2048 + t][1024] bf16
{
    __shared__ __align__(16) ushort Ks[2][4096];
    __shared__ __align__(16) ushort Vs[2][4096];   // [d][k], swizzled

    const int bh = blockIdx.x;
    const int j = 15 - blockIdx.y;                 // heavy-first
    const int tid = threadIdx.x;
    const int wid = tid >> 6;
    const int lane = tid & 63;
    const int ql = lane & 31;                      // q column
    const int hi = lane >> 5;                      // 0/1

    const ushort* Kg = Kb + (size_t)bh * T_SEQ * HD;
    const ushort* Vg = Vt + (size_t)bh * HD * T_SEQ;

    const int srow = tid >> 3;             // staging: 0..31
    const int sco = (tid & 7) * 8;
    const int ssw = sco ^ ((srow & 7) << 3);
    const int sdst0 = srow * 64 + ssw;
    const int sdst1 = (srow + 32) * 64 + ssw;

    const int b = bh >> 4, h = bh & 15;
    ushort* AOg = AO + (size_t)b * T_SEQ * DM + h * HD;

    const int q0 = j * 128;
    const int qlo = q0 + wid * 32;
    const int ntiles = 2 * j + 2;

    // Q B-frags: qb[ds] = Q[qlo+ql][ds*16 + hi*8 .. +8]
    short8 qb[4];
    {
        const ushort* Qg = Qb + ((size_t)bh * T_SEQ + qlo) * HD;
        #pragma unroll
        for (int ds = 0; ds < 4; ++ds)
            qb[ds] = *(const short8*)(Qg + (size_t)ql * HD + ds * 16 + hi * 8);
    }

    f32x16 po[2] = {};      // O^T accum
    float lp = 0.f;         // per-lane partial row sum (exact; static-max)

    short8 rk0, rk1, rv0, rv1;
    rk0 = *(const short8*)(Kg + (size_t)srow * HD + sco);
    rk1 = *(const short8*)(Kg + (size_t)(srow + 32) * HD + sco);
    rv0 = *(const short8*)(Vg + (size_t)srow * T_SEQ + sco);
    rv1 = *(const short8*)(Vg + (size_t)(srow + 32) * T_SEQ + sco);
    *(short8*)(&Ks[0][sdst0]) = rk0;  *(short8*)(&Ks[0][sdst1]) = rk1;
    *(short8*)(&Vs[0][sdst0]) = rv0;  *(short8*)(&Vs[0][sdst1]) = rv1;
    {
        const int nk0 = 64;
        rk0 = *(const short8*)(Kg + (size_t)(nk0 + srow) * HD + sco);
        rk1 = *(const short8*)(Kg + (size_t)(nk0 + srow + 32) * HD + sco);
        rv0 = *(const short8*)(Vg + (size_t)srow * T_SEQ + nk0 + sco);
        rv1 = *(const short8*)(Vg + (size_t)(srow + 32) * T_SEQ + nk0 + sco);
    }
    __syncthreads();

    for (int tt = 0; tt < ntiles; ++tt) {
        const int k0 = tt * 64;
        const int cur = tt & 1;
        if (tt + 1 < ntiles) {
            const int nxt = cur ^ 1;
            *(short8*)(&Ks[nxt][sdst0]) = rk0;  *(short8*)(&Ks[nxt][sdst1]) = rk1;
            *(short8*)(&Vs[nxt][sdst0]) = rv0;  *(short8*)(&Vs[nxt][sdst1]) = rv1;
            if (tt + 2 < ntiles) {
                const int nk0 = (tt + 2) * 64;
                rk0 = *(const short8*)(Kg + (size_t)(nk0 + srow) * HD + sco);
                rk1 = *(const short8*)(Kg + (size_t)(nk0 + srow + 32) * HD + sco);
                rv0 = *(const short8*)(Vg + (size_t)srow * T_SEQ + nk0 + sco);
                rv1 = *(const short8*)(Vg + (size_t)(srow + 32) * T_SEQ + nk0 + sco);
            }
        }

        if (k0 <= qlo + 31) {
            const ushort* ksb = Ks[cur];
            const ushort* vsb = Vs[cur];

            short8 vf[2][4];
            #pragma unroll
            for (int db = 0; db < 2; ++db)
                #pragma unroll
                for (int sl = 0; sl < 4; ++sl) {
                    int row = db * 32 + ql;
                    int slot = (sl * 2 + hi) ^ (row & 7);
                    vf[db][sl] = *(const short8*)(&vsb[row * 64 + slot * 8]);
                }

            f32x16 sp[2] = {};
            __builtin_amdgcn_s_setprio(1);
            #pragma unroll
            for (int kb = 0; kb < 2; ++kb) {
                #pragma unroll
                for (int ds = 0; ds < 4; ++ds) {
                    int row = kb * 32 + ql;
                    int slot = (ds * 2 + hi) ^ (row & 7);
                    short8 kf = *(const short8*)(&ksb[row * 64 + slot * 8]);
                    sp[kb] = __builtin_amdgcn_mfma_f32_32x32x16_bf16(kf, qb[ds], sp[kb], 0, 0, 0);
                }
            }
            __builtin_amdgcn_s_setprio(0);

            if (k0 + 63 > qlo) {
                #pragma unroll
                for (int kb = 0; kb < 2; ++kb) {
                    const int lim = qlo + ql - k0 - kb * 32 - 4 * hi;
                    #pragma unroll
                    for (int r = 0; r < 16; ++r) {
                        const int c = (r & 3) + 8 * (r >> 2);
                        sp[kb][r] = (c <= lim) ? sp[kb][r] : -INFINITY;
                    }
                }
            }

            float rs = 0.f;
            #pragma unroll
            for (int kb = 0; kb < 2; ++kb)
                #pragma unroll
                for (int r = 0; r < 16; ++r) {
                    float p;
                    asm("v_exp_f32 %0, %1" : "=v"(p) : "v"(sp[kb][r]));
                    sp[kb][r] = p;
                    rs += p;
                }
            lp += rs;

            #pragma unroll
            for (int kb = 0; kb < 2; ++kb) {
                #pragma unroll
                for (int ks16 = 0; ks16 < 2; ++ks16) {
                    unsigned int x0, x1, y0, y1;
                    const int rb0 = ks16 * 2, rb1 = ks16 * 2 + 1;
                    asm("v_cvt_pk_bf16_f32 %0, %1, %2" : "=v"(x0)
                        : "v"(sp[kb][4 * rb0 + 0]), "v"(sp[kb][4 * rb0 + 1]));
                    asm("v_cvt_pk_bf16_f32 %0, %1, %2" : "=v"(x1)
                        : "v"(sp[kb][4 * rb0 + 2]), "v"(sp[kb][4 * rb0 + 3]));
                    asm("v_cvt_pk_bf16_f32 %0, %1, %2" : "=v"(y0)
                        : "v"(sp[kb][4 * rb1 + 0]), "v"(sp[kb][4 * rb1 + 1]));
                    asm("v_cvt_pk_bf16_f32 %0, %1, %2" : "=v"(y1)
                        : "v"(sp[kb][4 * rb1 + 2]), "v"(sp[kb][4 * rb1 + 3]));
                    asm("v_permlane32_swap_b32 %0, %1" : "+v"(x0), "+v"(y0));
                    asm("v_permlane32_swap_b32 %0, %1" : "+v"(x1), "+v"(y1));
                    union { unsigned int w[4]; short8 s8; } pb;
                    pb.w[0] = x0; pb.w[1] = x1; pb.w[2] = y0; pb.w[3] = y1;
                    const int sl = kb * 2 + ks16;
                    __builtin_amdgcn_s_setprio(1);
                    po[0] = __builtin_amdgcn_mfma_f32_32x32x16_bf16(vf[0][sl], pb.s8, po[0], 0, 0, 0);
                    po[1] = __builtin_amdgcn_mfma_f32_32x32x16_bf16(vf[1][sl], pb.s8, po[1], 0, 0, 0);
                    __builtin_amdgcn_s_setprio(0);
                }
            }
        }
        __syncthreads();
    }

    lp += __shfl_xor(lp, 32);
    const float inv = 1.f / lp;
    const int q = qlo + ql;
    #pragma unroll
    for (int db = 0; db < 2; ++db) {
        #pragma unroll
        for (int rb = 0; rb < 4; ++rb) {
            unsigned int w0, w1;
            float f0 = po[db][4 * rb + 0] * inv, f1 = po[db][4 * rb + 1] * inv;
            float f2 = po[db][4 * rb + 2] * inv, f3 = po[db][4 * rb + 3] * inv;
            asm("v_cvt_pk_bf16_f32 %0, %1, %2" : "=v"(w0) : "v"(f0), "v"(f1));
            asm("v_cvt_pk_bf16_f32 %0, %1, %2" : "=v"(w1) : "v"(f2), "v"(f3));
            uint2 wv; wv.x = w0; wv.y = w1;
            *(uint2*)(AOg + (size_t)q * DM + db * 32 + 8 * rb + 4 * hi) = wv;
        }
    }
}

extern "C" void kernel_launch(void* const* d_in, const int* in_sizes, int n_in,
                              void* d_out, int out_size, void* d_ws, size_t ws_size,
                              hipStream_t stream) {
    const float* x      = (const float*)d_in[0];
    const float* W_qkv  = (const float*)d_in[1];
    const float* b_qkv  = (const float*)d_in[2];
    const float* W_proj = (const float*)d_in[3];
    const float* b_proj = (const float*)d_in[4];
    float* out = (float*)d_out;

    const size_t perbuf = (size_t)4 * NH * T_SEQ * HD;
    ushort* Qb  = (ushort*)d_ws;
    ushort* Kb  = Qb + perbuf;
    ushort* Vt  = Kb + perbuf;
    ushort* AO  = Vt + perbuf;
    ushort* Wqt = AO;                    // consumed by qkv_mfma before attn writes AO
    ushort* Wpt = Qb;                    // written after attn consumed Qb
    ushort* Xb  = (ushort*)d_out;        // d_out as scratch, overwritten by proj

    // prep: X->bf16 (4096 blocks) + W_qkv^T (768 blocks), one launch
    hipLaunchKernelGGL(prep, dim3(4096 + 768), dim3(256), 0, stream, x, Xb, W_qkv, Wqt);
    hipLaunchKernelGGL(qkv_mfma, dim3(24, 64), dim3(256), 0, stream,
                       Xb, Wqt, b_qkv, Qb, Kb, Vt);
    hipLaunchKernelGGL(attn_mfma, dim3(64, 16), dim3(256), 0, stream,
                       Qb, Kb, Vt, AO);
    hipLaunchKernelGGL(transpose_w, dim3(16, 16), dim3(256), 0, stream, W_proj, Wpt, DM);
    hipLaunchKernelGGL(proj_mfma, dim3(8, 64), dim3(256), 0, stream,
                       AO, Wpt, b_proj, out);
}